// Round 12
// baseline (179.188 us; speedup 1.0000x reference)
//
#include <hip/hip_runtime.h>
#include <hip/hip_bf16.h>

// obs (4096,138) f32 | obstacles (4096,5,128) f32 | act (4096,2) f32
// ow1 (22,256) ob1(256) ow2 (256,256) ob2(256)
// qw1 (396,256) qb1(256) qw2 (256,256) qb2(256) qw3 (256,1) qb3(1)
// out: (4096,) f32

typedef __attribute__((ext_vector_type(8))) short short8;
typedef __attribute__((ext_vector_type(4))) float f32x4;
typedef __attribute__((ext_vector_type(16))) float f32x16;

#define MFMA16(A, B, C) __builtin_amdgcn_mfma_f32_16x16x32_bf16(A, B, C, 0, 0, 0)
#define MFMA32(A, B, C) __builtin_amdgcn_mfma_f32_32x32x16_bf16(A, B, C, 0, 0, 0)

__device__ __forceinline__ unsigned short f2b(float f) {
  __hip_bfloat16 h = __float2bfloat16(f);
  return __builtin_bit_cast(unsigned short, h);
}
__device__ __forceinline__ float b2f(unsigned short u) {
  unsigned v = ((unsigned)u) << 16;
  return __builtin_bit_cast(float, v);
}
// fast pack: round-half-up (+0x8000) then take hi16 of both via one v_perm.
__device__ __forceinline__ unsigned pk2f(float a, float b) {
  unsigned ua = __builtin_bit_cast(unsigned, a) + 0x8000u;
  unsigned ub = __builtin_bit_cast(unsigned, b) + 0x8000u;
  return __builtin_amdgcn_perm(ub, ua, 0x07060302u);
}

// ---------------------------------------------------------------------------
// Kernel 0: pack weights (R10 layout: ow2q is 32x32 B-frag).
//  ow1q: A-frag layout (16x16x32) for layer1-swapped (K pad 32)
//  ow2q: B-frag layout for 32x32x16: idx=((ks*2+h)*256+n)*8+j ->
//        ow2[ks*16+h*8+j][n]   (ks=0..15, h=0..1)
//  qw1h/l, qw2h/l: B-frag layout (16x16x32), hi/lo split (head kernel)
// ---------------------------------------------------------------------------
__global__ __launch_bounds__(256) void pack_weights(
    const float* __restrict__ ow1, const float* __restrict__ ow2,
    const float* __restrict__ qw1, const float* __restrict__ qw2,
    unsigned short* __restrict__ ow1q, unsigned short* __restrict__ ow2q,
    unsigned short* __restrict__ qw1h, unsigned short* __restrict__ qw1l,
    unsigned short* __restrict__ qw2h, unsigned short* __restrict__ qw2l) {
  int i = blockIdx.x * 256 + threadIdx.x;  // 0..106495
  if (i < 8192) {
    int j = i & 7;
    int l15 = (i >> 3) & 15;
    int quad = (i >> 7) & 3;
    int mt = (i >> 9) & 15;
    int k = quad * 8 + j;
    float v = (k < 22) ? ow1[k * 256 + (mt * 16 + l15)] : 0.f;
    ow1q[i] = f2b(v);
  }
  if (i < 65536) {
    int j = i & 7;
    int n = (i >> 3) & 255;
    // ow2q: 32x32x16 B-frag order
    int hh = (i >> 11) & 1;
    int ks = i >> 12;  // 0..15
    int k32 = ks * 16 + hh * 8 + j;
    ow2q[i] = f2b(ow2[k32 * 256 + n]);
    // qw2: 16x16x32 B-frag order, hi/lo
    int qq = i >> 11;
    int k = (qq >> 2) * 32 + (qq & 3) * 8 + j;
    float w = qw2[k * 256 + n];
    unsigned short h = f2b(w);
    qw2h[i] = h;
    qw2l[i] = f2b(w - b2f(h));
  }
  if (i < 106496) {
    int j = i & 7;
    int n = (i >> 3) & 255;
    int qq = i >> 11;  // 0..51 = kb*4+quad
    int k = (qq >> 2) * 32 + (qq & 3) * 8 + j;
    float w = (k < 396) ? qw1[k * 256 + n] : 0.f;
    unsigned short h = f2b(w);
    qw1h[i] = h;
    qw1l[i] = f2b(w - b2f(h));
  }
}

// ---------------------------------------------------------------------------
// Kernel 1 (round 12): 128 rows/block, 512 threads (8 waves), 2 blocks/CU.
// Layer 1: 16x16x32 swapped (R8 structure).
// Layer 2: 32x32x16, wave grid (wm=wave>>2 in 0..1, wn=wave&3 in 0..3);
//   wave owns 2 M-tiles(32) x 2 N-tiles(32): A_rep=4 (LDS halved vs R8),
//   B_rep=2 (L2-cached), MFMA pipe -24% (8.07cyc/32KF).
// 32x32x16 layouts (HW-validated in R10): A[m=lane&31][k=(lane>>5)*8+j] |
//   B[k][n=lane&31] | C/D col=lane&31, row=(reg&3)+8*(reg>>2)+4*(lane>>5).
// Pool: per-wave partials, wm-halves combined via small LDS array.
// ---------------------------------------------------------------------------
#define XSTR 40   // xs row stride in shorts
#define HSTR 264  // h1 row stride in shorts

__global__ __launch_bounds__(512, 4) void obstacle_kernel(
    const float* __restrict__ obs, const float* __restrict__ obstacles,
    const unsigned short* __restrict__ ow1q,
    const unsigned short* __restrict__ ow2q,
    const float* __restrict__ ob1, const float* __restrict__ ob2,
    unsigned short* __restrict__ poolH, unsigned short* __restrict__ poolL) {
  __shared__ unsigned short xs[128 * XSTR];  // 10240 B
  __shared__ unsigned short h1[128 * HSTR];  // 67584 B
  __shared__ float poolP[2][256];            // 2048 B
  __shared__ float maskS[128];
  __shared__ unsigned short vehB[32];

  const int b = blockIdx.x;
  const int tid = threadIdx.x;

  if (tid < 18) vehB[tid] = f2b(obs[b * 138 + tid]);
  if (tid < 128) maskS[tid] = obstacles[b * 640 + 512 + tid];
  __syncthreads();

  // Build x rows (2 threads per row, tid<256): [0:18]=veh, [18:22]=obst.
  if (tid < 256) {
    int n = tid >> 1;
    int half = tid & 1;
    unsigned short* wr = &xs[n * XSTR + half * 16];
    if (half == 0) {
      unsigned short r01[16];
#pragma unroll
      for (int k = 0; k < 16; k++) r01[k] = vehB[k];
      *(short8*)(wr + 0) = *(short8*)&r01[0];
      *(short8*)(wr + 8) = *(short8*)&r01[8];
    } else {
      unsigned short r2[8];
      r2[0] = vehB[16];
      r2[1] = vehB[17];
#pragma unroll
      for (int d = 0; d < 4; d++)
        r2[2 + d] = f2b(obstacles[b * 640 + d * 128 + n]);
      r2[6] = 0; r2[7] = 0;
      *(short8*)(wr + 0) = *(short8*)&r2[0];
      short8 z = {0, 0, 0, 0, 0, 0, 0, 0};
      *(short8*)(wr + 8) = z;
    }
  }
  __syncthreads();

  const int wave = tid >> 6;   // 0..7
  const int lane = tid & 63;
  const int quad = lane >> 4;
  const int l15 = lane & 15;

  // ---- Layer 1 (swapped, D = W1^T x X^T, 16x16x32): wave owns 2 n_out
  //      tiles (wave*2, wave*2+1), all 8 row tiles. Bias in C-init. ----
  {
    const unsigned short* wp = &ow1q[wave * 1024 + quad * 128 + l15 * 8];
    short8 wfr[2];
#pragma unroll
    for (int i = 0; i < 2; i++) wfr[i] = *(const short8*)(wp + i * 512);

    const unsigned short* bxp = &xs[l15 * XSTR + quad * 8];
    short8 bx[8];
#pragma unroll
    for (int nt = 0; nt < 8; nt++)
      bx[nt] = *(const short8*)(bxp + nt * 16 * XSTR);

    unsigned short* wrb = &h1[l15 * HSTR + wave * 32 + quad * 4];

#pragma unroll
    for (int i = 0; i < 2; i++) {
      f32x4 cinit = *(const f32x4*)&ob1[wave * 32 + i * 16 + quad * 4];
      f32x4 acc1[8];
#pragma unroll
      for (int nt = 0; nt < 8; nt++) acc1[nt] = MFMA16(wfr[i], bx[nt], cinit);
#pragma unroll
      for (int nt = 0; nt < 8; nt++) {
        float v0 = fmaxf(acc1[nt][0], 0.f);
        float v1 = fmaxf(acc1[nt][1], 0.f);
        float v2 = fmaxf(acc1[nt][2], 0.f);
        float v3 = fmaxf(acc1[nt][3], 0.f);
        uint2 pk;
        pk.x = pk2f(v0, v1);
        pk.y = pk2f(v2, v3);
        *(uint2*)(wrb + nt * 16 * HSTR + i * 16) = pk;
      }
    }
  }
  __syncthreads();

  // ---- Layer 2 (32x32x16): wave (wm, wn) owns rows [wm*64, wm*64+64),
  //      cols [wn*64, wn*64+64). Bias in C-init; B prefetched. ----
  const int wm = wave >> 2;    // 0..1
  const int wn = wave & 3;     // 0..3
  const int h32 = lane >> 5;   // 0/1
  const int l31 = lane & 31;

  f32x16 acc[2][2];
#pragma unroll
  for (int t = 0; t < 2; t++) {
    float bv = ob2[wn * 64 + t * 32 + l31];
#pragma unroll
    for (int mt = 0; mt < 2; mt++)
#pragma unroll
      for (int r = 0; r < 16; r++) acc[mt][t][r] = bv;
  }

  const unsigned short* bp = &ow2q[(h32 * 256 + wn * 64 + l31) * 8];
  const unsigned short* h1r = &h1[(wm * 64 + l31) * HSTR + h32 * 8];
  short8 bcur[2], bnxt[2];
#pragma unroll
  for (int t = 0; t < 2; t++) bcur[t] = *(const short8*)(bp + t * 256);

#pragma unroll 1
  for (int ks = 0; ks < 16; ks++) {
    if (ks < 15) {
#pragma unroll
      for (int t = 0; t < 2; t++)
        bnxt[t] = *(const short8*)(bp + 4096 + t * 256);
    }
    short8 afr[2];
#pragma unroll
    for (int mt = 0; mt < 2; mt++)
      afr[mt] = *(const short8*)(h1r + mt * 32 * HSTR);
#pragma unroll
    for (int mt = 0; mt < 2; mt++)
#pragma unroll
      for (int t = 0; t < 2; t++) acc[mt][t] = MFMA32(afr[mt], bcur[t], acc[mt][t]);
    bp += 4096;
    h1r += 16;
    if (ks < 15) {
#pragma unroll
      for (int t = 0; t < 2; t++) bcur[t] = bnxt[t];
    }
  }

  // ---- Pool: lane rows = wm*64 + mt*32 + 8*(reg>>2) + 4*h32 + (reg&3);
  //      combine half-waves (shfl 32) then wm-halves (LDS). ----
  f32x4 mk[2][4];
#pragma unroll
  for (int mt = 0; mt < 2; mt++)
#pragma unroll
    for (int g = 0; g < 4; g++)
      mk[mt][g] = *(const f32x4*)&maskS[wm * 64 + mt * 32 + g * 8 + h32 * 4];

#pragma unroll
  for (int t = 0; t < 2; t++) {
    float s = 0.f;
#pragma unroll
    for (int mt = 0; mt < 2; mt++) {
#pragma unroll
      for (int g = 0; g < 4; g++) {
#pragma unroll
        for (int j = 0; j < 4; j++) {
          float v = fmaxf(acc[mt][t][g * 4 + j], 0.f);
          s = fmaf(mk[mt][g][j], v, s);
        }
      }
    }
    s += __shfl_xor(s, 32);
    if (h32 == 0) poolP[wm][wn * 64 + t * 32 + l31] = s;
  }
  __syncthreads();

  if (tid < 256) {
    float s = poolP[0][tid] + poolP[1][tid];
    unsigned short sh = (unsigned short)(__builtin_bit_cast(unsigned, s) >> 16);
    poolH[b * 256 + tid] = sh;  // truncated hi; lo captures remainder
    poolL[b * 256 + tid] = f2b(s - b2f(sh));
  }
}

// ---------------------------------------------------------------------------
// Kernel 2: head MLP via MFMA, hi/lo bf16 split, weight-frag register
// prefetch (R11). 256 blocks x 1024 threads (16 waves, wave owns 1 N-tile).
// ---------------------------------------------------------------------------
__global__ __launch_bounds__(1024) void head_mfma(
    const float* __restrict__ obs, const float* __restrict__ act,
    const unsigned short* __restrict__ poolH,
    const unsigned short* __restrict__ poolL,
    const unsigned short* __restrict__ qw1h,
    const unsigned short* __restrict__ qw1l,
    const unsigned short* __restrict__ qw2h,
    const unsigned short* __restrict__ qw2l,
    const float* __restrict__ qb1, const float* __restrict__ qb2,
    const float* __restrict__ qw3, const float* __restrict__ qb3,
    float* __restrict__ out) {
  const int CSTR = 424;
  const int HSTRQ = 264;
  __shared__ unsigned short combH[16 * 424], combL[16 * 424];
  __shared__ unsigned short h1H[16 * 264], h1L[16 * 264];
  __shared__ float wred[16][16];

  const int tid = threadIdx.x;
  const int r0 = blockIdx.x * 16;

  // Build comb hi/lo: [obs(138) | pooled(256) | act(2) | pad->416]
  for (int idx = tid; idx < 16 * 416; idx += 1024) {
    int m = idx / 416;
    int k = idx - m * 416;
    unsigned short hi, lo;
    if (k < 138) {
      float v = obs[(r0 + m) * 138 + k];
      hi = f2b(v);
      lo = f2b(v - b2f(hi));
    } else if (k < 394) {
      hi = poolH[(r0 + m) * 256 + (k - 138)];
      lo = poolL[(r0 + m) * 256 + (k - 138)];
    } else if (k < 396) {
      float v = act[(r0 + m) * 2 + (k - 394)];
      hi = f2b(v);
      lo = f2b(v - b2f(hi));
    } else {
      hi = 0; lo = 0;
    }
    combH[m * CSTR + k] = hi;
    combL[m * CSTR + k] = lo;
  }
  __syncthreads();

  const int wave = tid >> 6;  // 0..15 = N-tile
  const int lane = tid & 63;
  const int quad = lane >> 4;
  const int l15 = lane & 15;
  const int n = wave * 16 + l15;

  // ---- Layer 1: 13 kb, weight frags prefetched one kb ahead ----
  f32x4 acc = {0.f, 0.f, 0.f, 0.f}, accm = {0.f, 0.f, 0.f, 0.f};
  {
    const unsigned short* b1hp = &qw1h[(quad * 256 + n) * 8];
    const unsigned short* b1lp = &qw1l[(quad * 256 + n) * 8];
    const unsigned short* aHp = &combH[l15 * CSTR + quad * 8];
    const unsigned short* aLp = &combL[l15 * CSTR + quad * 8];
    short8 bh = *(const short8*)b1hp;
    short8 bl = *(const short8*)b1lp;
    short8 bhn, bln;
#pragma unroll 1
    for (int kb = 0; kb < 13; kb++) {
      if (kb < 12) {
        bhn = *(const short8*)(b1hp + 8192);
        bln = *(const short8*)(b1lp + 8192);
      }
      short8 ah = *(const short8*)aHp;
      short8 al = *(const short8*)aLp;
      acc = MFMA16(ah, bh, acc);
      accm = MFMA16(ah, bl, accm);
      accm = MFMA16(al, bh, accm);
      b1hp += 8192; b1lp += 8192; aHp += 32; aLp += 32;
      if (kb < 12) { bh = bhn; bl = bln; }
    }
  }
  {
    float bias = qb1[n];
#pragma unroll
    for (int r = 0; r < 4; r++) {
      int m = quad * 4 + r;
      float v = fmaxf(acc[r] + accm[r] + bias, 0.f);
      unsigned short hi = f2b(v);
      h1H[m * HSTRQ + n] = hi;
      h1L[m * HSTRQ + n] = f2b(v - b2f(hi));
    }
  }
  __syncthreads();

  // ---- Layer 2: 8 kb, weight frags prefetched one kb ahead ----
  f32x4 a2 = {0.f, 0.f, 0.f, 0.f}, a2m = {0.f, 0.f, 0.f, 0.f};
  {
    const unsigned short* b2hp = &qw2h[(quad * 256 + n) * 8];
    const unsigned short* b2lp = &qw2l[(quad * 256 + n) * 8];
    const unsigned short* aHp = &h1H[l15 * HSTRQ + quad * 8];
    const unsigned short* aLp = &h1L[l15 * HSTRQ + quad * 8];
    short8 bh = *(const short8*)b2hp;
    short8 bl = *(const short8*)b2lp;
    short8 bhn, bln;
#pragma unroll 1
    for (int kb = 0; kb < 8; kb++) {
      if (kb < 7) {
        bhn = *(const short8*)(b2hp + 8192);
        bln = *(const short8*)(b2lp + 8192);
      }
      short8 ah = *(const short8*)aHp;
      short8 al = *(const short8*)aLp;
      a2 = MFMA16(ah, bh, a2);
      a2m = MFMA16(ah, bl, a2m);
      a2m = MFMA16(al, bh, a2m);
      b2hp += 8192; b2lp += 8192; aHp += 32; aLp += 32;
      if (kb < 7) { bh = bhn; bl = bln; }
    }
  }

  // ---- Layer 3: f32 dot with qw3, reduce over the wave's 16 cols ----
  {
    float w3 = qw3[n];
    float qb2n = qb2[n];
#pragma unroll
    for (int r = 0; r < 4; r++) {
      float v = fmaxf(a2[r] + a2m[r] + qb2n, 0.f);
      float s = v * w3;
      s += __shfl_xor(s, 1);
      s += __shfl_xor(s, 2);
      s += __shfl_xor(s, 4);
      s += __shfl_xor(s, 8);
      if (l15 == 0) wred[wave][quad * 4 + r] = s;
    }
  }
  __syncthreads();
  if (tid < 16) {
    float s = qb3[0];
#pragma unroll
    for (int w = 0; w < 16; w++) s += wred[w][tid];
    out[r0 + tid] = s;
  }
}

// ---------------------------------------------------------------------------
extern "C" void kernel_launch(void* const* d_in, const int* in_sizes, int n_in,
                              void* d_out, int out_size, void* d_ws, size_t ws_size,
                              hipStream_t stream) {
  const float* obs       = (const float*)d_in[0];
  const float* obstacles = (const float*)d_in[1];
  const float* act       = (const float*)d_in[2];
  const float* ow1       = (const float*)d_in[3];
  const float* ob1       = (const float*)d_in[4];
  const float* ow2       = (const float*)d_in[5];
  const float* ob2       = (const float*)d_in[6];
  const float* qw1       = (const float*)d_in[7];
  const float* qb1       = (const float*)d_in[8];
  const float* qw2       = (const float*)d_in[9];
  const float* qb2       = (const float*)d_in[10];
  const float* qw3       = (const float*)d_in[11];
  const float* qb3       = (const float*)d_in[12];
  float* out = (float*)d_out;

  unsigned short* ow1q = (unsigned short*)d_ws;   // 8192
  unsigned short* ow2q = ow1q + 8192;             // 65536 (32x32 B-frag)
  unsigned short* qw1h = ow2q + 65536;            // 106496
  unsigned short* qw1l = qw1h + 106496;           // 106496
  unsigned short* qw2h = qw1l + 106496;           // 65536
  unsigned short* qw2l = qw2h + 65536;            // 65536
  unsigned short* poolH = qw2l + 65536;           // 4096*256
  unsigned short* poolL = poolH + 1048576;        // 4096*256

  pack_weights<<<416, 256, 0, stream>>>(ow1, ow2, qw1, qw2, ow1q, ow2q, qw1h,
                                        qw1l, qw2h, qw2l);
  obstacle_kernel<<<4096, 512, 0, stream>>>(obs, obstacles, ow1q, ow2q, ob1,
                                            ob2, poolH, poolL);
  head_mfma<<<256, 1024, 0, stream>>>(obs, act, poolH, poolL, qw1h, qw1l,
                                      qw2h, qw2l, qb1, qb2, qw3, qb3, out);
}

// Round 13
// 167.054 us; speedup vs baseline: 1.0726x; 1.0726x over previous
//
#include <hip/hip_runtime.h>
#include <hip/hip_bf16.h>

// obs (4096,138) f32 | obstacles (4096,5,128) f32 | act (4096,2) f32
// ow1 (22,256) ob1(256) ow2 (256,256) ob2(256)
// qw1 (396,256) qb1(256) qw2 (256,256) qb2(256) qw3 (256,1) qb3(1)
// out: (4096,) f32
//
// FINAL (round 13 = exact round-8 config, the measured optimum):
//  - obstacle: 4096 blocks x 512 thr, 16x16x32 MFMA, layer-2 tiling
//    8 M-tiles x 2 N-tiles (B-read-once, 4 waves/SIMD) — 81-84us.
//  - head: MFMA hi/lo-bf16 split (3-term), 256 blocks x 1024 thr.
//  - measured floor: pipe-sum (MFMA 37us + LDS ~40us + VMEM ~13us,
//    partially overlapped) ~= 80us; all other tilings measured worse.

typedef __attribute__((ext_vector_type(8))) short short8;
typedef __attribute__((ext_vector_type(4))) float f32x4;

#define MFMA16(A, B, C) __builtin_amdgcn_mfma_f32_16x16x32_bf16(A, B, C, 0, 0, 0)

__device__ __forceinline__ unsigned short f2b(float f) {
  __hip_bfloat16 h = __float2bfloat16(f);
  return __builtin_bit_cast(unsigned short, h);
}
__device__ __forceinline__ float b2f(unsigned short u) {
  unsigned v = ((unsigned)u) << 16;
  return __builtin_bit_cast(float, v);
}
// fast pack: round-half-up (+0x8000) then take hi16 of both via one v_perm.
__device__ __forceinline__ unsigned pk2f(float a, float b) {
  unsigned ua = __builtin_bit_cast(unsigned, a) + 0x8000u;
  unsigned ub = __builtin_bit_cast(unsigned, b) + 0x8000u;
  return __builtin_amdgcn_perm(ub, ua, 0x07060302u);
}

// ---------------------------------------------------------------------------
// Kernel 0: pack weights.
// ---------------------------------------------------------------------------
__global__ __launch_bounds__(256) void pack_weights(
    const float* __restrict__ ow1, const float* __restrict__ ow2,
    const float* __restrict__ qw1, const float* __restrict__ qw2,
    unsigned short* __restrict__ ow1q, unsigned short* __restrict__ ow2p,
    unsigned short* __restrict__ qw1h, unsigned short* __restrict__ qw1l,
    unsigned short* __restrict__ qw2h, unsigned short* __restrict__ qw2l) {
  int i = blockIdx.x * 256 + threadIdx.x;  // 0..106495
  if (i < 8192) {
    int j = i & 7;
    int l15 = (i >> 3) & 15;
    int quad = (i >> 7) & 3;
    int mt = (i >> 9) & 15;
    int k = quad * 8 + j;
    float v = (k < 22) ? ow1[k * 256 + (mt * 16 + l15)] : 0.f;
    ow1q[i] = f2b(v);
  }
  if (i < 65536) {
    int j = i & 7;
    int n = (i >> 3) & 255;
    int qq = i >> 11;
    int k = (qq >> 2) * 32 + (qq & 3) * 8 + j;
    ow2p[i] = f2b(ow2[k * 256 + n]);
    float w = qw2[k * 256 + n];
    unsigned short h = f2b(w);
    qw2h[i] = h;
    qw2l[i] = f2b(w - b2f(h));
  }
  if (i < 106496) {
    int j = i & 7;
    int n = (i >> 3) & 255;
    int qq = i >> 11;  // 0..51 = kb*4+quad
    int k = (qq >> 2) * 32 + (qq & 3) * 8 + j;
    float w = (k < 396) ? qw1[k * 256 + n] : 0.f;
    unsigned short h = f2b(w);
    qw1h[i] = h;
    qw1l[i] = f2b(w - b2f(h));
  }
}

// ---------------------------------------------------------------------------
// Kernel 1: 128 rows/block, 512 threads (8 waves), 2 blocks/CU (LDS 78.4KB).
// Layer-2 wave tiling: 8 M-tiles x 2 N-tiles -> B-frag reuse 8, ow2p read
// exactly once per block; B prefetched one kb ahead.
// ---------------------------------------------------------------------------
#define XSTR 40   // xs row stride in shorts
#define HSTR 264  // h1 row stride in shorts

__global__ __launch_bounds__(512, 4) void obstacle_kernel(
    const float* __restrict__ obs, const float* __restrict__ obstacles,
    const unsigned short* __restrict__ ow1q,
    const unsigned short* __restrict__ ow2p,
    const float* __restrict__ ob1, const float* __restrict__ ob2,
    unsigned short* __restrict__ poolH, unsigned short* __restrict__ poolL) {
  __shared__ unsigned short xs[128 * XSTR];  // 10240 B
  __shared__ unsigned short h1[128 * HSTR];  // 67584 B
  __shared__ float maskS[128];
  __shared__ unsigned short vehB[32];

  const int b = blockIdx.x;
  const int tid = threadIdx.x;

  if (tid < 18) vehB[tid] = f2b(obs[b * 138 + tid]);
  if (tid < 128) maskS[tid] = obstacles[b * 640 + 512 + tid];
  __syncthreads();

  // Build x rows (2 threads per row, tid<256): [0:18]=veh, [18:22]=obst.
  if (tid < 256) {
    int n = tid >> 1;
    int half = tid & 1;
    unsigned short* wr = &xs[n * XSTR + half * 16];
    if (half == 0) {
      unsigned short r01[16];
#pragma unroll
      for (int k = 0; k < 16; k++) r01[k] = vehB[k];
      *(short8*)(wr + 0) = *(short8*)&r01[0];
      *(short8*)(wr + 8) = *(short8*)&r01[8];
    } else {
      unsigned short r2[8];
      r2[0] = vehB[16];
      r2[1] = vehB[17];
#pragma unroll
      for (int d = 0; d < 4; d++)
        r2[2 + d] = f2b(obstacles[b * 640 + d * 128 + n]);
      r2[6] = 0; r2[7] = 0;
      *(short8*)(wr + 0) = *(short8*)&r2[0];
      short8 z = {0, 0, 0, 0, 0, 0, 0, 0};
      *(short8*)(wr + 8) = z;
    }
  }
  __syncthreads();

  const int wave = tid >> 6;   // 0..7
  const int lane = tid & 63;
  const int quad = lane >> 4;
  const int l15 = lane & 15;

  // ---- Layer 1 (swapped, D = W1^T x X^T): wave owns 2 n_out tiles
  //      (wave*2, wave*2+1), all 8 row tiles. Bias in C-init. ----
  {
    const unsigned short* wp = &ow1q[wave * 1024 + quad * 128 + l15 * 8];
    short8 wfr[2];
#pragma unroll
    for (int i = 0; i < 2; i++) wfr[i] = *(const short8*)(wp + i * 512);

    const unsigned short* bxp = &xs[l15 * XSTR + quad * 8];
    short8 bx[8];
#pragma unroll
    for (int nt = 0; nt < 8; nt++)
      bx[nt] = *(const short8*)(bxp + nt * 16 * XSTR);

    unsigned short* wrb = &h1[l15 * HSTR + wave * 32 + quad * 4];

#pragma unroll
    for (int i = 0; i < 2; i++) {
      f32x4 cinit = *(const f32x4*)&ob1[wave * 32 + i * 16 + quad * 4];
      f32x4 acc1[8];
#pragma unroll
      for (int nt = 0; nt < 8; nt++) acc1[nt] = MFMA16(wfr[i], bx[nt], cinit);
#pragma unroll
      for (int nt = 0; nt < 8; nt++) {
        float v0 = fmaxf(acc1[nt][0], 0.f);
        float v1 = fmaxf(acc1[nt][1], 0.f);
        float v2 = fmaxf(acc1[nt][2], 0.f);
        float v3 = fmaxf(acc1[nt][3], 0.f);
        uint2 pk;
        pk.x = pk2f(v0, v1);
        pk.y = pk2f(v2, v3);
        *(uint2*)(wrb + nt * 16 * HSTR + i * 16) = pk;
      }
    }
  }
  __syncthreads();

  // ---- Layer 2: wave owns ALL 8 mt, nt = wave*2..+1 (B reuse 8);
  //      bias in C-init; B prefetched one kb ahead. ----
  f32x4 acc[8][2];
#pragma unroll
  for (int t = 0; t < 2; t++) {
    float bv = ob2[wave * 32 + t * 16 + l15];
    f32x4 bvec = {bv, bv, bv, bv};
#pragma unroll
    for (int mt = 0; mt < 8; mt++) acc[mt][t] = bvec;
  }

  const unsigned short* bp = &ow2p[(quad * 256 + wave * 32 + l15) * 8];
  const unsigned short* h1r = &h1[l15 * HSTR + quad * 8];
  short8 bcur[2], bnxt[2];
#pragma unroll
  for (int t = 0; t < 2; t++) bcur[t] = *(const short8*)(bp + t * 128);

#pragma unroll 1
  for (int kb = 0; kb < 8; kb++) {
    if (kb < 7) {
#pragma unroll
      for (int t = 0; t < 2; t++)
        bnxt[t] = *(const short8*)(bp + 8192 + t * 128);
    }
    short8 afr[8];
#pragma unroll
    for (int mt = 0; mt < 8; mt++)
      afr[mt] = *(const short8*)(h1r + mt * 16 * HSTR);
#pragma unroll
    for (int mt = 0; mt < 8; mt++)
#pragma unroll
      for (int t = 0; t < 2; t++) acc[mt][t] = MFMA16(afr[mt], bcur[t], acc[mt][t]);
    bp += 8192;
    h1r += 32;
    if (kb < 7) {
#pragma unroll
      for (int t = 0; t < 2; t++) bcur[t] = bnxt[t];
    }
  }

  // ---- Pool epilogue: pooled[n] = sum_m mask[m]*relu(h2[m][n]);
  //      column n owned by exactly one wave. ----
  f32x4 mk[8];
  const float* mkp = &maskS[quad * 4];
#pragma unroll
  for (int mt = 0; mt < 8; mt++) mk[mt] = *(const f32x4*)(mkp + mt * 16);

#pragma unroll
  for (int t = 0; t < 2; t++) {
    float s = 0.f;
#pragma unroll
    for (int mt = 0; mt < 8; mt++) {
#pragma unroll
      for (int r = 0; r < 4; r++) {
        float v = fmaxf(acc[mt][t][r], 0.f);
        s = fmaf(mk[mt][r], v, s);
      }
    }
    s += __shfl_xor(s, 16);
    s += __shfl_xor(s, 32);
    if (quad == 0) {
      int n = wave * 32 + t * 16 + l15;
      unsigned short sh = (unsigned short)(__builtin_bit_cast(unsigned, s) >> 16);
      poolH[b * 256 + n] = sh;  // truncated hi; lo captures remainder
      poolL[b * 256 + n] = f2b(s - b2f(sh));
    }
  }
}

// ---------------------------------------------------------------------------
// Kernel 2: head MLP via MFMA, hi/lo bf16 split (3-term). 256 blocks x 1024
// threads (16 waves, wave owns 1 N-tile). Layer 3 f32 VALU.
// ---------------------------------------------------------------------------
__global__ __launch_bounds__(1024) void head_mfma(
    const float* __restrict__ obs, const float* __restrict__ act,
    const unsigned short* __restrict__ poolH,
    const unsigned short* __restrict__ poolL,
    const unsigned short* __restrict__ qw1h,
    const unsigned short* __restrict__ qw1l,
    const unsigned short* __restrict__ qw2h,
    const unsigned short* __restrict__ qw2l,
    const float* __restrict__ qb1, const float* __restrict__ qb2,
    const float* __restrict__ qw3, const float* __restrict__ qb3,
    float* __restrict__ out) {
  const int CSTR = 424;
  const int HSTRQ = 264;
  __shared__ unsigned short combH[16 * 424], combL[16 * 424];
  __shared__ unsigned short h1H[16 * 264], h1L[16 * 264];
  __shared__ float wred[16][16];

  const int tid = threadIdx.x;
  const int r0 = blockIdx.x * 16;

  // Build comb hi/lo: [obs(138) | pooled(256) | act(2) | pad->416]
  for (int idx = tid; idx < 16 * 416; idx += 1024) {
    int m = idx / 416;
    int k = idx - m * 416;
    unsigned short hi, lo;
    if (k < 138) {
      float v = obs[(r0 + m) * 138 + k];
      hi = f2b(v);
      lo = f2b(v - b2f(hi));
    } else if (k < 394) {
      hi = poolH[(r0 + m) * 256 + (k - 138)];
      lo = poolL[(r0 + m) * 256 + (k - 138)];
    } else if (k < 396) {
      float v = act[(r0 + m) * 2 + (k - 394)];
      hi = f2b(v);
      lo = f2b(v - b2f(hi));
    } else {
      hi = 0; lo = 0;
    }
    combH[m * CSTR + k] = hi;
    combL[m * CSTR + k] = lo;
  }
  __syncthreads();

  const int wave = tid >> 6;  // 0..15 = N-tile
  const int lane = tid & 63;
  const int quad = lane >> 4;
  const int l15 = lane & 15;
  const int n = wave * 16 + l15;

  // ---- Layer 1: 13 kb ----
  f32x4 acc = {0.f, 0.f, 0.f, 0.f}, accm = {0.f, 0.f, 0.f, 0.f};
#pragma unroll 1
  for (int kb = 0; kb < 13; kb++) {
    int ao = l15 * CSTR + kb * 32 + quad * 8;
    short8 ah = *(const short8*)&combH[ao];
    short8 al = *(const short8*)&combL[ao];
    int off = ((kb * 4 + quad) * 256 + n) * 8;
    short8 bh = *(const short8*)&qw1h[off];
    short8 bl = *(const short8*)&qw1l[off];
    acc = MFMA16(ah, bh, acc);
    accm = MFMA16(ah, bl, accm);
    accm = MFMA16(al, bh, accm);
  }
  {
    float bias = qb1[n];
#pragma unroll
    for (int r = 0; r < 4; r++) {
      int m = quad * 4 + r;
      float v = fmaxf(acc[r] + accm[r] + bias, 0.f);
      unsigned short hi = f2b(v);
      h1H[m * HSTRQ + n] = hi;
      h1L[m * HSTRQ + n] = f2b(v - b2f(hi));
    }
  }
  __syncthreads();

  // ---- Layer 2: 8 kb ----
  f32x4 a2 = {0.f, 0.f, 0.f, 0.f}, a2m = {0.f, 0.f, 0.f, 0.f};
#pragma unroll 1
  for (int kb = 0; kb < 8; kb++) {
    int ao = l15 * HSTRQ + kb * 32 + quad * 8;
    short8 ah = *(const short8*)&h1H[ao];
    short8 al = *(const short8*)&h1L[ao];
    int off = ((kb * 4 + quad) * 256 + n) * 8;
    short8 bh = *(const short8*)&qw2h[off];
    short8 bl = *(const short8*)&qw2l[off];
    a2 = MFMA16(ah, bh, a2);
    a2m = MFMA16(ah, bl, a2m);
    a2m = MFMA16(al, bh, a2m);
  }

  // ---- Layer 3: f32 dot with qw3, reduce over the wave's 16 cols ----
  {
    float w3 = qw3[n];
    float qb2n = qb2[n];
#pragma unroll
    for (int r = 0; r < 4; r++) {
      float v = fmaxf(a2[r] + a2m[r] + qb2n, 0.f);
      float s = v * w3;
      s += __shfl_xor(s, 1);
      s += __shfl_xor(s, 2);
      s += __shfl_xor(s, 4);
      s += __shfl_xor(s, 8);
      if (l15 == 0) wred[wave][quad * 4 + r] = s;
    }
  }
  __syncthreads();
  if (tid < 16) {
    float s = qb3[0];
#pragma unroll
    for (int w = 0; w < 16; w++) s += wred[w][tid];
    out[r0 + tid] = s;
  }
}

// ---------------------------------------------------------------------------
extern "C" void kernel_launch(void* const* d_in, const int* in_sizes, int n_in,
                              void* d_out, int out_size, void* d_ws, size_t ws_size,
                              hipStream_t stream) {
  const float* obs       = (const float*)d_in[0];
  const float* obstacles = (const float*)d_in[1];
  const float* act       = (const float*)d_in[2];
  const float* ow1       = (const float*)d_in[3];
  const float* ob1       = (const float*)d_in[4];
  const float* ow2       = (const float*)d_in[5];
  const float* ob2       = (const float*)d_in[6];
  const float* qw1       = (const float*)d_in[7];
  const float* qb1       = (const float*)d_in[8];
  const float* qw2       = (const float*)d_in[9];
  const float* qb2       = (const float*)d_in[10];
  const float* qw3       = (const float*)d_in[11];
  const float* qb3       = (const float*)d_in[12];
  float* out = (float*)d_out;

  unsigned short* ow1q = (unsigned short*)d_ws;   // 8192
  unsigned short* ow2p = ow1q + 8192;             // 65536
  unsigned short* qw1h = ow2p + 65536;            // 106496
  unsigned short* qw1l = qw1h + 106496;           // 106496
  unsigned short* qw2h = qw1l + 106496;           // 65536
  unsigned short* qw2l = qw2h + 65536;            // 65536
  unsigned short* poolH = qw2l + 65536;           // 4096*256
  unsigned short* poolL = poolH + 1048576;        // 4096*256

  pack_weights<<<416, 256, 0, stream>>>(ow1, ow2, qw1, qw2, ow1q, ow2p, qw1h,
                                        qw1l, qw2h, qw2l);
  obstacle_kernel<<<4096, 512, 0, stream>>>(obs, obstacles, ow1q, ow2p, ob1,
                                            ob2, poolH, poolL);
  head_mfma<<<256, 1024, 0, stream>>>(obs, act, poolH, poolL, qw1h, qw1l,
                                      qw2h, qw2l, qb1, qb2, qw3, qb3, out);
}